// Round 3
// baseline (290.096 us; speedup 1.0000x reference)
//
#include <hip/hip_runtime.h>
#include <stdint.h>

// SMHA: sigmoid multi-head attention, L=2048 B=2 E=1024 H=16 hd=64.
// convert(f32->bf16) -> inproj GEMM -> fused sigmoid attention
// -> avg_weights (head-summed sigmoid QK) -> outproj GEMM.

#define L_SEQ 2048
#define NBATCH 2
#define EMB 1024
#define NHEAD 16
#define HD 64
#define MROWS 4096  // B*L

typedef __bf16 bf16x8 __attribute__((ext_vector_type(8)));
typedef float f32x4 __attribute__((ext_vector_type(4)));
typedef float f32x16 __attribute__((ext_vector_type(16)));

__device__ __forceinline__ unsigned short f2bf(float f) {
  union { float f; uint32_t u; } v; v.f = f;
  uint32_t u = v.u;
  u += 0x7fffu + ((u >> 16) & 1u);  // RNE
  return (unsigned short)(u >> 16);
}

__device__ __forceinline__ unsigned short f2bf_fast(float f) {
  union { float f; uint32_t u; } v; v.f = f;
  return (unsigned short)((v.u + 0x8000u) >> 16);
}

__device__ __forceinline__ void gl_lds16(const void* gptr, void* ldsptr) {
  const uint32_t* g = reinterpret_cast<const uint32_t*>(gptr);
  auto* l = reinterpret_cast<__attribute__((address_space(3))) uint32_t*>(
      reinterpret_cast<uintptr_t>(ldsptr));
  __builtin_amdgcn_global_load_lds(g, l, 16, 0, 0);
}

__device__ __forceinline__ f32x4 mfma16(bf16x8 a, bf16x8 b, f32x4 c) {
  return __builtin_amdgcn_mfma_f32_16x16x32_bf16(a, b, c, 0, 0, 0);
}

__device__ __forceinline__ f32x16 mfma32(bf16x8 a, bf16x8 b, f32x16 c) {
  return __builtin_amdgcn_mfma_f32_32x32x16_bf16(a, b, c, 0, 0, 0);
}

__device__ __forceinline__ float fast_sigmoid(float x) {
  float e = __expf(-x);
  return __builtin_amdgcn_rcpf(1.0f + e);
}

// ---------------------------------------------------------------- K0: convert
__global__ __launch_bounds__(256) void k_convert(
    const float* __restrict__ qin, const float* __restrict__ kin,
    const float* __restrict__ vin, const float* __restrict__ win,
    const float* __restrict__ wo,
    unsigned short* __restrict__ Xq, unsigned short* __restrict__ Xk,
    unsigned short* __restrict__ Xv, unsigned short* __restrict__ Wb,
    unsigned short* __restrict__ Wob) {
  const int row = blockIdx.x;
  const int t = threadIdx.x;
  const float* src;
  unsigned short* dst;
  int srow;
  size_t drow;
  if (row < 3 * MROWS) {
    const int which = row >> 12;
    const int m = row & (MROWS - 1);
    const int b = m >> 11, l = m & (L_SEQ - 1);
    srow = l * NBATCH + b;  // input rows are (l, b)
    drow = (size_t)m;
    src = which == 0 ? qin : (which == 1 ? kin : vin);
    dst = which == 0 ? Xq : (which == 1 ? Xk : Xv);
  } else if (row < 3 * MROWS + 3072) {
    srow = row - 3 * MROWS; drow = (size_t)srow; src = win; dst = Wb;
  } else {
    srow = row - (3 * MROWS + 3072); drow = (size_t)srow; src = wo; dst = Wob;
  }
  const float4 vv = *(const float4*)(src + (size_t)srow * EMB + t * 4);
  ushort4 o;
  o.x = f2bf(vv.x); o.y = f2bf(vv.y); o.z = f2bf(vv.z); o.w = f2bf(vv.w);
  *(ushort4*)(dst + drow * EMB + t * 4) = o;
}

// --------------------------------------------------- shared GEMM core (BT)
__device__ __forceinline__ void gemm_core(
    const unsigned short* __restrict__ A, const unsigned short* __restrict__ Bm,
    int m0, int n0, unsigned short* sA, unsigned short* sB, f32x4 acc[4][4]) {
  const int tid = threadIdx.x;
  const int wave = tid >> 6;
  const int lane = tid & 63;
  const int quad = lane >> 4;
  const int l16 = lane & 15;
  const int wm = (wave >> 1) * 64;
  const int wn = (wave & 1) * 64;
  const int srow = lane >> 2;
  const int scol = lane & 3;

  for (int mi = 0; mi < 4; ++mi)
    for (int ni = 0; ni < 4; ++ni)
      acc[mi][ni] = (f32x4){0.f, 0.f, 0.f, 0.f};

  for (int k0 = 0; k0 < EMB; k0 += 32) {
    __syncthreads();
    for (int i = 0; i < 2; ++i) {
      const int p = wave * 2 + i;
      const int r = p * 16 + srow;
      const int c = scol ^ ((r >> 1) & 3);
      gl_lds16(A + (size_t)(m0 + r) * EMB + k0 + c * 8, sA + p * 512);
      gl_lds16(Bm + (size_t)(n0 + r) * EMB + k0 + c * 8, sB + p * 512);
    }
    __syncthreads();
    bf16x8 af[4], bfr[4];
    for (int mi = 0; mi < 4; ++mi) {
      const int r = wm + mi * 16 + l16;
      const int cp = quad ^ ((r >> 1) & 3);
      af[mi] = *(const bf16x8*)(sA + r * 32 + cp * 8);
    }
    for (int ni = 0; ni < 4; ++ni) {
      const int r = wn + ni * 16 + l16;
      const int cp = quad ^ ((r >> 1) & 3);
      bfr[ni] = *(const bf16x8*)(sB + r * 32 + cp * 8);
    }
    for (int mi = 0; mi < 4; ++mi)
      for (int ni = 0; ni < 4; ++ni)
        acc[mi][ni] = mfma16(af[mi], bfr[ni], acc[mi][ni]);
  }
}

// ---------------------------------------------------------------- K1: inproj
// z=0: q (scaled 1/8) -> (b,h,l,d); z=1: k -> (b,h,l,d); z=2: v -> (b,h,d,l)
// via swizzled LDS transpose + coalesced b128 stores.
__global__ __launch_bounds__(256) void k_inproj(
    const unsigned short* __restrict__ Xq, const unsigned short* __restrict__ Xk,
    const unsigned short* __restrict__ Xv, const unsigned short* __restrict__ Wb,
    const float* __restrict__ bias,
    unsigned short* __restrict__ qb, unsigned short* __restrict__ kb,
    unsigned short* __restrict__ vb) {
  __shared__ __attribute__((aligned(16))) unsigned short sA[128 * 32];
  __shared__ __attribute__((aligned(16))) unsigned short sB[128 * 32];
  __shared__ __attribute__((aligned(16))) unsigned short sT[128 * 128];
  const int z = blockIdx.z;
  const unsigned short* A = z == 0 ? Xq : (z == 1 ? Xk : Xv);
  const int n0 = blockIdx.x * 128, m0 = blockIdx.y * 128;
  f32x4 acc[4][4];
  gemm_core(A, Wb + (size_t)z * EMB * EMB, m0, n0, sA, sB, acc);

  const int tid = threadIdx.x, wave = tid >> 6, lane = tid & 63;
  const int quad = lane >> 4, l16 = lane & 15;
  const int wm = (wave >> 1) * 64, wn = (wave & 1) * 64;
  const int bb = m0 >> 11, lbase = m0 & (L_SEQ - 1);

  if (z == 2) {
    // pack rows of C^T into swizzled LDS tile [n][m-chunks]
    for (int ni = 0; ni < 4; ++ni) {
      const int n = wn + ni * 16 + l16;
      const float bv = bias[2 * EMB + n0 + n];
      const int x = (n & 15) << 1;
      for (int mi = 0; mi < 4; ++mi) {
        const int mchunk = ((wm + mi * 16) >> 2) + quad;
        const int slot = mchunk ^ x;
        ushort4 pk;
        pk.x = f2bf(acc[mi][ni][0] + bv);
        pk.y = f2bf(acc[mi][ni][1] + bv);
        pk.z = f2bf(acc[mi][ni][2] + bv);
        pk.w = f2bf(acc[mi][ni][3] + bv);
        *(ushort4*)(sT + (size_t)n * 128 + slot * 4) = pk;
      }
    }
    __syncthreads();
    // coalesced store: thread -> (row n, half), 8 x b128
    const int n = tid >> 1, hf = tid & 1;
    const int ng = n0 + n;
    const int h = ng >> 6, d = ng & 63;
    unsigned short* dst =
        vb + ((size_t)(bb * NHEAD + h) * HD + d) * L_SEQ + lbase + hf * 64;
    const int x = (n & 15) << 1;
    for (int j = 0; j < 8; ++j) {
      const int c2 = hf * 16 + j * 2;  // even chunk base
      const int slot = c2 ^ x;         // x even -> slot,slot+1 adjacent
      uint4 vd = *(const uint4*)(sT + (size_t)n * 128 + slot * 4);
      *(uint4*)(dst + j * 8) = vd;
    }
  } else {
    const float scale = (z == 0) ? 0.125f : 1.0f;
    unsigned short* dst01 = (z == 0) ? qb : kb;
    for (int ni = 0; ni < 4; ++ni) {
      const int n = n0 + wn + ni * 16 + l16;
      const float bv = bias[z * EMB + n];
      const int h = n >> 6, d = n & 63;
      for (int mi = 0; mi < 4; ++mi) {
        for (int r = 0; r < 4; ++r) {
          const int m = m0 + wm + mi * 16 + quad * 4 + r;
          const int b = m >> 11, l = m & (L_SEQ - 1);
          dst01[((size_t)(b * NHEAD + h) * L_SEQ + l) * HD + d] =
              f2bf((acc[mi][ni][r] + bv) * scale);
        }
      }
    }
  }
}

// --------------------------------------------------------------- K2: attention
// 512 thr / 8 waves. Block = (b*H+h, l-tile 128), s-step 64, K/V double-buffered
// (2 barriers/iter, DMA prefetch under QK+sigmoid). QK: 16x16 S^T. PV+den:
// 32x32x16, den via ones-B-frag reusing PV's A fragment (same C-layout rows).
__global__ __launch_bounds__(512) void k_attn(
    const unsigned short* __restrict__ qb, const unsigned short* __restrict__ kb,
    const unsigned short* __restrict__ vb, unsigned short* __restrict__ oh) {
  __shared__ __attribute__((aligned(16))) unsigned short sQ[128 * 64];
  __shared__ __attribute__((aligned(16))) unsigned short sK[2][64 * 64];
  __shared__ __attribute__((aligned(16))) unsigned short sV[2][64 * 64];
  __shared__ __attribute__((aligned(16))) unsigned short sP[128 * 72];

  const int bh = blockIdx.x;
  const int b = bh >> 4, h = bh & 15;
  const int l0 = blockIdx.y * 128;
  const unsigned short* qg = qb + ((size_t)bh * L_SEQ + l0) * HD;
  const unsigned short* kg = kb + (size_t)bh * L_SEQ * HD;
  const unsigned short* vg = vb + (size_t)bh * HD * L_SEQ;

  const int tid = threadIdx.x, wave = tid >> 6, lane = tid & 63;
  const int quad = lane >> 4, l16 = lane & 15;
  const int l32 = lane & 31, lh = lane >> 5;
  const int sr8 = lane >> 3, sc8 = lane & 7;
  const int sh = (wave >> 2) * 32;  // QK s-half
  const int lq = (wave & 3) * 32;   // QK l-quarter
  const int lt = wave & 3;          // PV l-tile
  const int dt = wave >> 2;         // PV d-tile

  // prologue: stage Q once + K/V iter 0 into buf 0
  for (int i = 0; i < 2; ++i) {
    const int p = wave * 2 + i;
    const int r = p * 8 + sr8;
    const int c = sc8 ^ (r & 7);
    gl_lds16(qg + (size_t)r * HD + c * 8, sQ + p * 512);
  }
  if (wave < 4) {
    for (int i = 0; i < 2; ++i) {
      const int p = wave * 2 + i;
      const int r = p * 8 + sr8;
      const int c = sc8 ^ (r & 7);
      gl_lds16(kg + (size_t)r * HD + c * 8, sK[0] + p * 512);
    }
  } else {
    for (int i = 0; i < 2; ++i) {
      const int p = (wave - 4) * 2 + i;
      const int r = p * 8 + sr8;
      const int c = sc8 ^ (r & 7);
      gl_lds16(vg + (size_t)r * L_SEQ + c * 8, sV[0] + p * 512);
    }
  }

  f32x16 oacc, dacc;
  for (int i = 0; i < 16; ++i) { oacc[i] = 0.f; dacc[i] = 0.f; }
  bf16x8 ones;
  for (int j = 0; j < 8; ++j) ones[j] = (__bf16)1.0f;

  for (int it = 0; it < 32; ++it) {
    __syncthreads();  // buf(it) visible; all waves past PV(it-1)
    const int cur = it & 1;
    if (it < 31) {  // prefetch next K/V under QK+sigmoid
      const int nxt = cur ^ 1;
      const int s1 = (it + 1) * 64;
      if (wave < 4) {
        for (int i = 0; i < 2; ++i) {
          const int p = wave * 2 + i;
          const int r = p * 8 + sr8;
          const int c = sc8 ^ (r & 7);
          gl_lds16(kg + (size_t)(s1 + r) * HD + c * 8, sK[nxt] + p * 512);
        }
      } else {
        for (int i = 0; i < 2; ++i) {
          const int p = (wave - 4) * 2 + i;
          const int r = p * 8 + sr8;
          const int c = sc8 ^ (r & 7);
          gl_lds16(vg + (size_t)r * L_SEQ + s1 + c * 8, sV[nxt] + p * 512);
        }
      }
    }

    // S^T tile: wave covers s[sh,sh+32) x l[lq,lq+32)
    f32x4 st[2][2];
    for (int smi = 0; smi < 2; ++smi)
      for (int lni = 0; lni < 2; ++lni) st[smi][lni] = (f32x4){0.f, 0.f, 0.f, 0.f};
    for (int kk = 0; kk < HD; kk += 32) {
      bf16x8 a[2], bq[2];
      for (int smi = 0; smi < 2; ++smi) {
        const int r = sh + smi * 16 + l16;
        const int c = ((kk >> 3) + quad) ^ (r & 7);
        a[smi] = *(const bf16x8*)(sK[cur] + r * 64 + c * 8);
      }
      for (int lni = 0; lni < 2; ++lni) {
        const int r = lq + lni * 16 + l16;
        const int c = ((kk >> 3) + quad) ^ (r & 7);
        bq[lni] = *(const bf16x8*)(sQ + r * 64 + c * 8);
      }
      for (int smi = 0; smi < 2; ++smi)
        for (int lni = 0; lni < 2; ++lni)
          st[smi][lni] = mfma16(a[smi], bq[lni], st[smi][lni]);
    }

    // sigmoid + perm-pack -> sP[l][s_local], stride 72
    for (int lni = 0; lni < 2; ++lni) {
      const int lrow = lq + lni * 16 + l16;
      for (int smi = 0; smi < 2; ++smi) {
        uint32_t u[4];
        for (int r = 0; r < 4; ++r) {
          union { float f; uint32_t i; } cv;
          cv.f = fast_sigmoid(st[smi][lni][r]);
          u[r] = cv.i + 0x8000u;  // round-half-up bf16
        }
        uint2 pk;
        pk.x = __builtin_amdgcn_perm(u[1], u[0], 0x07060302u);
        pk.y = __builtin_amdgcn_perm(u[3], u[2], 0x07060302u);
        *(uint2*)(sP + (size_t)lrow * 72 + sh + smi * 16 + quad * 4) = pk;
      }
    }
    __syncthreads();  // sP visible (also drains prefetch DMA)

    // PV 32x32: wave = l-tile lt (32 l) x d-tile dt (32 d), full 64 s
    const unsigned short* prow = sP + (size_t)(lt * 32 + l32) * 72;
    const int vrow = dt * 32 + l32;
    for (int kk = 0; kk < 4; ++kk) {
      bf16x8 ap = *(const bf16x8*)(prow + kk * 16 + lh * 8);
      const int c = (kk * 2 + lh) ^ (vrow & 7);
      bf16x8 bv = *(const bf16x8*)(sV[cur] + vrow * 64 + c * 8);
      oacc = mfma32(ap, bv, oacc);
      dacc = mfma32(ap, ones, dacc);
    }
  }

  // epilogue: den rows align with oacc rows in 32x32 C-layout
  for (int r = 0; r < 16; ++r) {
    const int row = (r & 3) + 8 * (r >> 2) + 4 * lh;
    const int l = l0 + lt * 32 + row;
    const float rden = __builtin_amdgcn_rcpf(dacc[r] + 1e-4f);
    oh[((size_t)(b * L_SEQ + l)) * EMB + h * HD + dt * 32 + l32] =
        f2bf_fast(oacc[r] * rden);
  }
}

// ---------------------------------------------------------------- K3: avg
// 512 thr / 8 waves. Block = (s-tile 256, l-tile 128, b); grid = 256 blocks.
// Per head: 1 barrier + double-buffered Q/K staging; 32x32 MFMA, 4 tiles/wave;
// f32 accumulation (no bf16 pack). Trans-pipe bound (~14 us device floor).
__global__ __launch_bounds__(512) void k_avg(
    const unsigned short* __restrict__ qb, const unsigned short* __restrict__ kb,
    float* __restrict__ avg) {
  __shared__ __attribute__((aligned(16))) unsigned short sQ[2][128 * 64];
  __shared__ __attribute__((aligned(16))) unsigned short sK[2][256 * 64];
  const int ss0 = blockIdx.x * 256, l0 = blockIdx.y * 128, b = blockIdx.z;
  const int tid = threadIdx.x, wave = tid >> 6, lane = tid & 63;
  const int l32 = lane & 31, lh = lane >> 5;
  const int sr8 = lane >> 3, sc8 = lane & 7;
  const int mt = wave & 3;            // l-tile (32)
  const int ntg = (wave >> 2) * 4;    // first of 4 s-tiles (32 each)

  const unsigned short* qg0 = qb + ((size_t)(b * NHEAD) * L_SEQ + l0) * HD;
  const unsigned short* kg0 = kb + ((size_t)(b * NHEAD) * L_SEQ + ss0) * HD;
  const size_t hstride = (size_t)L_SEQ * HD;

  // stage head 0
  for (int i = 0; i < 2; ++i) {
    const int p = wave * 2 + i;
    const int r = p * 8 + sr8;
    const int c = sc8 ^ (r & 7);
    gl_lds16(qg0 + (size_t)r * HD + c * 8, sQ[0] + p * 512);
  }
  for (int i = 0; i < 4; ++i) {
    const int p = wave * 4 + i;
    const int r = p * 8 + sr8;
    const int c = sc8 ^ (r & 7);
    gl_lds16(kg0 + (size_t)r * HD + c * 8, sK[0] + p * 512);
  }

  f32x16 av[4];
  for (int t = 0; t < 4; ++t)
    for (int i = 0; i < 16; ++i) av[t][i] = 0.f;

  for (int h = 0; h < NHEAD; ++h) {
    __syncthreads();  // buf(h) visible, prev reads done
    const int cur = h & 1;
    if (h < NHEAD - 1) {
      const int nxt = cur ^ 1;
      const unsigned short* qg = qg0 + (size_t)(h + 1) * hstride;
      const unsigned short* kg = kg0 + (size_t)(h + 1) * hstride;
      for (int i = 0; i < 2; ++i) {
        const int p = wave * 2 + i;
        const int r = p * 8 + sr8;
        const int c = sc8 ^ (r & 7);
        gl_lds16(qg + (size_t)r * HD + c * 8, sQ[nxt] + p * 512);
      }
      for (int i = 0; i < 4; ++i) {
        const int p = wave * 4 + i;
        const int r = p * 8 + sr8;
        const int c = sc8 ^ (r & 7);
        gl_lds16(kg + (size_t)r * HD + c * 8, sK[nxt] + p * 512);
      }
    }

    f32x16 scr[4];
    for (int t = 0; t < 4; ++t)
      for (int i = 0; i < 16; ++i) scr[t][i] = 0.f;
    const int qrow = mt * 32 + l32;
    for (int kk = 0; kk < 4; ++kk) {
      const int cq = (kk * 2 + lh) ^ (qrow & 7);
      bf16x8 aq = *(const bf16x8*)(sQ[cur] + qrow * 64 + cq * 8);
      for (int t = 0; t < 4; ++t) {
        const int krow = (ntg + t) * 32 + l32;
        const int ck = (kk * 2 + lh) ^ (krow & 7);
        bf16x8 bk = *(const bf16x8*)(sK[cur] + krow * 64 + ck * 8);
        scr[t] = mfma32(aq, bk, scr[t]);
      }
    }
    for (int t = 0; t < 4; ++t)
      for (int r = 0; r < 16; ++r)
        av[t][r] += fast_sigmoid(scr[t][r]);
  }

  for (int t = 0; t < 4; ++t) {
    for (int r = 0; r < 16; ++r) {
      const int l = l0 + mt * 32 + (r & 3) + 8 * (r >> 2) + 4 * lh;
      const int s = ss0 + (ntg + t) * 32 + l32;
      avg[((size_t)b * L_SEQ + l) * L_SEQ + s] = av[t][r] * 0.0625f;
    }
  }
}

// ---------------------------------------------------------------- K4: outproj
__global__ __launch_bounds__(256) void k_outproj(
    const unsigned short* __restrict__ OH, const unsigned short* __restrict__ Wob,
    const float* __restrict__ ob, float* __restrict__ out) {
  __shared__ __attribute__((aligned(16))) unsigned short sA[128 * 32];
  __shared__ __attribute__((aligned(16))) unsigned short sB[128 * 32];
  const int n0 = blockIdx.x * 128, m0 = blockIdx.y * 128;
  f32x4 acc[4][4];
  gemm_core(OH, Wob, m0, n0, sA, sB, acc);

  const int tid = threadIdx.x, wave = tid >> 6, lane = tid & 63;
  const int quad = lane >> 4, l16 = lane & 15;
  const int wm = (wave >> 1) * 64, wn = (wave & 1) * 64;
  for (int ni = 0; ni < 4; ++ni) {
    const int n = n0 + wn + ni * 16 + l16;
    const float bv = ob[n];
    for (int mi = 0; mi < 4; ++mi) {
      for (int r = 0; r < 4; ++r) {
        const int m = m0 + wm + mi * 16 + quad * 4 + r;
        const int b = m >> 11, l = m & (L_SEQ - 1);
        out[((size_t)l * NBATCH + b) * EMB + n] = acc[mi][ni][r] + bv;
      }
    }
  }
}

extern "C" void kernel_launch(void* const* d_in, const int* in_sizes, int n_in,
                              void* d_out, int out_size, void* d_ws, size_t ws_size,
                              hipStream_t stream) {
  (void)in_sizes; (void)n_in; (void)out_size;
  const float* qin = (const float*)d_in[0];
  const float* kin = (const float*)d_in[1];
  const float* vin = (const float*)d_in[2];
  const float* w   = (const float*)d_in[3];
  const float* bias = (const float*)d_in[4];
  const float* wo  = (const float*)d_in[5];
  const float* ob  = (const float*)d_in[6];
  float* out = (float*)d_out;

  unsigned short* Xq  = (unsigned short*)d_ws;
  unsigned short* Xk  = Xq + (size_t)MROWS * EMB;
  unsigned short* Xv  = Xk + (size_t)MROWS * EMB;
  unsigned short* Wb  = Xv + (size_t)MROWS * EMB;
  unsigned short* Wob = Wb + (size_t)3 * EMB * EMB;
  unsigned short* qbuf = Wob + (size_t)EMB * EMB;
  unsigned short* kbuf = qbuf + (size_t)MROWS * EMB;
  unsigned short* vbuf = kbuf + (size_t)MROWS * EMB;
  unsigned short* ohb  = vbuf + (size_t)MROWS * EMB;
  const size_t need = ((size_t)MROWS * EMB * 7 + (size_t)4 * EMB * EMB) * 2;
  if (ws_size < need) return;

  k_convert<<<16384, 256, 0, stream>>>(qin, kin, vin, w, wo, Xq, Xk, Xv, Wb, Wob);
  k_inproj<<<dim3(8, 32, 3), 256, 0, stream>>>(Xq, Xk, Xv, Wb, bias, qbuf, kbuf, vbuf);
  k_attn<<<dim3(32, 16), 512, 0, stream>>>(qbuf, kbuf, vbuf, ohb);
  k_avg<<<dim3(8, 16, 2), 512, 0, stream>>>(qbuf, kbuf, out + (size_t)MROWS * EMB);
  k_outproj<<<dim3(8, 32), 256, 0, stream>>>(ohb, Wob, ob, out);
}

// Round 4
// 284.005 us; speedup vs baseline: 1.0214x; 1.0214x over previous
//
#include <hip/hip_runtime.h>
#include <stdint.h>

// SMHA: sigmoid multi-head attention, L=2048 B=2 E=1024 H=16 hd=64.
// convert(f32->bf16) -> inproj GEMM -> fused sigmoid attention
// -> avg_weights (head-summed sigmoid QK) -> outproj GEMM.

#define L_SEQ 2048
#define NBATCH 2
#define EMB 1024
#define NHEAD 16
#define HD 64
#define MROWS 4096  // B*L

typedef __bf16 bf16x8 __attribute__((ext_vector_type(8)));
typedef float f32x4 __attribute__((ext_vector_type(4)));
typedef float f32x16 __attribute__((ext_vector_type(16)));

__device__ __forceinline__ unsigned short f2bf(float f) {
  union { float f; uint32_t u; } v; v.f = f;
  uint32_t u = v.u;
  u += 0x7fffu + ((u >> 16) & 1u);  // RNE
  return (unsigned short)(u >> 16);
}

__device__ __forceinline__ unsigned short f2bf_fast(float f) {
  union { float f; uint32_t u; } v; v.f = f;
  return (unsigned short)((v.u + 0x8000u) >> 16);
}

__device__ __forceinline__ void gl_lds16(const void* gptr, void* ldsptr) {
  const uint32_t* g = reinterpret_cast<const uint32_t*>(gptr);
  auto* l = reinterpret_cast<__attribute__((address_space(3))) uint32_t*>(
      reinterpret_cast<uintptr_t>(ldsptr));
  __builtin_amdgcn_global_load_lds(g, l, 16, 0, 0);
}

__device__ __forceinline__ f32x4 mfma16(bf16x8 a, bf16x8 b, f32x4 c) {
  return __builtin_amdgcn_mfma_f32_16x16x32_bf16(a, b, c, 0, 0, 0);
}

__device__ __forceinline__ f32x16 mfma32(bf16x8 a, bf16x8 b, f32x16 c) {
  return __builtin_amdgcn_mfma_f32_32x32x16_bf16(a, b, c, 0, 0, 0);
}

__device__ __forceinline__ float fast_sigmoid(float x) {
  float e = __expf(-x);
  return __builtin_amdgcn_rcpf(1.0f + e);
}

// ---------------------------------------------------------------- K0: convert
__global__ __launch_bounds__(256) void k_convert(
    const float* __restrict__ qin, const float* __restrict__ kin,
    const float* __restrict__ vin, const float* __restrict__ win,
    const float* __restrict__ wo,
    unsigned short* __restrict__ Xq, unsigned short* __restrict__ Xk,
    unsigned short* __restrict__ Xv, unsigned short* __restrict__ Wb,
    unsigned short* __restrict__ Wob) {
  const int row = blockIdx.x;
  const int t = threadIdx.x;
  const float* src;
  unsigned short* dst;
  int srow;
  size_t drow;
  if (row < 3 * MROWS) {
    const int which = row >> 12;
    const int m = row & (MROWS - 1);
    const int b = m >> 11, l = m & (L_SEQ - 1);
    srow = l * NBATCH + b;  // input rows are (l, b)
    drow = (size_t)m;
    src = which == 0 ? qin : (which == 1 ? kin : vin);
    dst = which == 0 ? Xq : (which == 1 ? Xk : Xv);
  } else if (row < 3 * MROWS + 3072) {
    srow = row - 3 * MROWS; drow = (size_t)srow; src = win; dst = Wb;
  } else {
    srow = row - (3 * MROWS + 3072); drow = (size_t)srow; src = wo; dst = Wob;
  }
  const float4 vv = *(const float4*)(src + (size_t)srow * EMB + t * 4);
  ushort4 o;
  o.x = f2bf(vv.x); o.y = f2bf(vv.y); o.z = f2bf(vv.z); o.w = f2bf(vv.w);
  *(ushort4*)(dst + drow * EMB + t * 4) = o;
}

// --------------------------------------------------- shared GEMM core (BT)
__device__ __forceinline__ void gemm_core(
    const unsigned short* __restrict__ A, const unsigned short* __restrict__ Bm,
    int m0, int n0, unsigned short* sA, unsigned short* sB, f32x4 acc[4][4]) {
  const int tid = threadIdx.x;
  const int wave = tid >> 6;
  const int lane = tid & 63;
  const int quad = lane >> 4;
  const int l16 = lane & 15;
  const int wm = (wave >> 1) * 64;
  const int wn = (wave & 1) * 64;
  const int srow = lane >> 2;
  const int scol = lane & 3;

  for (int mi = 0; mi < 4; ++mi)
    for (int ni = 0; ni < 4; ++ni)
      acc[mi][ni] = (f32x4){0.f, 0.f, 0.f, 0.f};

  for (int k0 = 0; k0 < EMB; k0 += 32) {
    __syncthreads();
    for (int i = 0; i < 2; ++i) {
      const int p = wave * 2 + i;
      const int r = p * 16 + srow;
      const int c = scol ^ ((r >> 1) & 3);
      gl_lds16(A + (size_t)(m0 + r) * EMB + k0 + c * 8, sA + p * 512);
      gl_lds16(Bm + (size_t)(n0 + r) * EMB + k0 + c * 8, sB + p * 512);
    }
    __syncthreads();
    bf16x8 af[4], bfr[4];
    for (int mi = 0; mi < 4; ++mi) {
      const int r = wm + mi * 16 + l16;
      const int cp = quad ^ ((r >> 1) & 3);
      af[mi] = *(const bf16x8*)(sA + r * 32 + cp * 8);
    }
    for (int ni = 0; ni < 4; ++ni) {
      const int r = wn + ni * 16 + l16;
      const int cp = quad ^ ((r >> 1) & 3);
      bfr[ni] = *(const bf16x8*)(sB + r * 32 + cp * 8);
    }
    for (int mi = 0; mi < 4; ++mi)
      for (int ni = 0; ni < 4; ++ni)
        acc[mi][ni] = mfma16(af[mi], bfr[ni], acc[mi][ni]);
  }
}

// ---------------------------------------------------------------- K1: inproj
// z=0: q (scaled 1/8) -> (b,h,l,d); z=1: k -> (b,h,l,d); z=2: v -> (b,h,d,l).
// All epilogues go through an LDS transpose tile; stores use 8-lanes-per-
// 128B-row-segment mapping so each store instr writes 8 full cache lines.
__global__ __launch_bounds__(256) void k_inproj(
    const unsigned short* __restrict__ Xq, const unsigned short* __restrict__ Xk,
    const unsigned short* __restrict__ Xv, const unsigned short* __restrict__ Wb,
    const float* __restrict__ bias,
    unsigned short* __restrict__ qb, unsigned short* __restrict__ kb,
    unsigned short* __restrict__ vb) {
  __shared__ __attribute__((aligned(16))) unsigned short sA[128 * 32];
  __shared__ __attribute__((aligned(16))) unsigned short sB[128 * 32];
  __shared__ __attribute__((aligned(16))) unsigned short sT[128 * 128];
  const int z = blockIdx.z;
  const unsigned short* A = z == 0 ? Xq : (z == 1 ? Xk : Xv);
  const int n0 = blockIdx.x * 128, m0 = blockIdx.y * 128;
  f32x4 acc[4][4];
  gemm_core(A, Wb + (size_t)z * EMB * EMB, m0, n0, sA, sB, acc);

  const int tid = threadIdx.x, wave = tid >> 6, lane = tid & 63;
  const int quad = lane >> 4, l16 = lane & 15;
  const int wm = (wave >> 1) * 64, wn = (wave & 1) * 64;
  const int bb = m0 >> 11, lbase = m0 & (L_SEQ - 1);
  const int lane8 = tid & 7, rowid = tid >> 3;

  if (z == 2) {
    // pack C^T rows into swizzled LDS tile [n][m-chunks of 4]
    for (int ni = 0; ni < 4; ++ni) {
      const int n = wn + ni * 16 + l16;
      const float bv = bias[2 * EMB + n0 + n];
      const int x = (n & 15) << 1;
      for (int mi = 0; mi < 4; ++mi) {
        const int mchunk = ((wm + mi * 16) >> 2) + quad;
        const int slot = mchunk ^ x;
        ushort4 pk;
        pk.x = f2bf(acc[mi][ni][0] + bv);
        pk.y = f2bf(acc[mi][ni][1] + bv);
        pk.z = f2bf(acc[mi][ni][2] + bv);
        pk.w = f2bf(acc[mi][ni][3] + bv);
        *(ushort4*)(sT + (size_t)n * 128 + slot * 4) = pk;
      }
    }
    __syncthreads();
    // store: row256 = (n, m-half); 8 lanes cover one 128B segment
    for (int p = 0; p < 8; ++p) {
      const int row = rowid + p * 32;  // 0..255
      const int n = row >> 1, hf = row & 1;
      const int x = (n & 15) << 1;
      const int c2 = hf * 16 + lane8 * 2;
      const int slot = c2 ^ x;  // x even -> slot,slot+1 adjacent
      uint4 vd = *(const uint4*)(sT + (size_t)n * 128 + slot * 4);
      const int ng = n0 + n;
      const int h = ng >> 6, d = ng & 63;
      unsigned short* dst =
          vb + ((size_t)(bb * NHEAD + h) * HD + d) * L_SEQ + lbase + hf * 64;
      *(uint4*)(dst + lane8 * 8) = vd;
    }
  } else {
    const float scale = (z == 0) ? 0.125f : 1.0f;
    unsigned short* dstp = (z == 0) ? qb : kb;
    // write C tile into sT[m][n ^ swz(m)] as b16 (quads land on disjoint
    // bank groups via the (m>>2)-based XOR)
    for (int ni = 0; ni < 4; ++ni) {
      const int n = wn + ni * 16 + l16;
      const float bv = bias[z * EMB + n0 + n];
      for (int mi = 0; mi < 4; ++mi) {
        for (int r = 0; r < 4; ++r) {
          const int m = wm + mi * 16 + quad * 4 + r;
          const int g = (m >> 2) & 7;
          sT[(size_t)m * 128 + (n ^ (g << 4))] =
              f2bf((acc[mi][ni][r] + bv) * scale);
        }
      }
    }
    __syncthreads();
    // store: row256 = (l, n-half); 8 lanes cover one 128B segment
    for (int p = 0; p < 8; ++p) {
      const int row = rowid + p * 32;
      const int l = row >> 1, hf = row & 1;
      const int g2 = ((l >> 2) & 7) << 1;
      const int c = hf * 8 + lane8;       // logical chunk of 8 n's
      const int slot = c ^ g2;
      uint4 vd = *(const uint4*)(sT + (size_t)l * 128 + slot * 8);
      const int ng = n0 + c * 8;
      const int h = ng >> 6, d = ng & 63;
      unsigned short* dst =
          dstp + ((size_t)(bb * NHEAD + h) * L_SEQ + lbase + l) * HD + d;
      *(uint4*)dst = vd;
    }
  }
}

// --------------------------------------------------------------- K2: attention
// (measured 66.7us in round 2 — reverted verbatim) 512 thr / 8 waves.
// Block = (b*H+h, l-tile 128), s-step 64. QK as S^T = K*Q^T; sigmoid +
// perm-pack -> sP; PV 16x16 with den via ones-MFMA (same C rows as oacc).
__global__ __launch_bounds__(512) void k_attn(
    const unsigned short* __restrict__ qb, const unsigned short* __restrict__ kb,
    const unsigned short* __restrict__ vb, unsigned short* __restrict__ oh) {
  __shared__ __attribute__((aligned(16))) unsigned short sQ[128 * 64];
  __shared__ __attribute__((aligned(16))) unsigned short sK[64 * 64];
  __shared__ __attribute__((aligned(16))) unsigned short sV[64 * 64];
  __shared__ __attribute__((aligned(16))) unsigned short sP[128 * 72];

  const int bh = blockIdx.x;
  const int b = bh >> 4, h = bh & 15;
  const int l0 = blockIdx.y * 128;
  const unsigned short* qg = qb + ((size_t)bh * L_SEQ + l0) * HD;
  const unsigned short* kg = kb + (size_t)bh * L_SEQ * HD;
  const unsigned short* vg = vb + (size_t)bh * HD * L_SEQ;

  const int tid = threadIdx.x, wave = tid >> 6, lane = tid & 63;
  const int quad = lane >> 4, l16 = lane & 15;
  const int sr8 = lane >> 3, sc8 = lane & 7;
  const int sh = (wave >> 2) * 32;  // QK: s-half
  const int lq = (wave & 3) * 32;   // QK: l-quarter

  for (int i = 0; i < 2; ++i) {
    const int p = wave * 2 + i;
    const int r = p * 8 + sr8;
    const int c = sc8 ^ (r & 7);
    gl_lds16(qg + (size_t)r * HD + c * 8, sQ + p * 512);
  }

  f32x4 oacc[4];
  for (int ni = 0; ni < 4; ++ni) oacc[ni] = (f32x4){0.f, 0.f, 0.f, 0.f};
  f32x4 dacc = (f32x4){0.f, 0.f, 0.f, 0.f};

  bf16x8 ones;
  for (int j = 0; j < 8; ++j) ones[j] = (__bf16)1.0f;

  for (int s0 = 0; s0 < L_SEQ; s0 += 64) {
    __syncthreads();
    if (wave < 4) {
      for (int i = 0; i < 2; ++i) {
        const int p = wave * 2 + i;
        const int r = p * 8 + sr8;
        const int c = sc8 ^ (r & 7);
        gl_lds16(kg + (size_t)(s0 + r) * HD + c * 8, sK + p * 512);
      }
    } else {
      for (int i = 0; i < 2; ++i) {
        const int p = (wave - 4) * 2 + i;
        const int r = p * 8 + sr8;
        const int c = sc8 ^ (r & 7);
        gl_lds16(vg + (size_t)r * L_SEQ + s0 + c * 8, sV + p * 512);
      }
    }
    __syncthreads();

    f32x4 st[2][2];
    for (int smi = 0; smi < 2; ++smi)
      for (int lni = 0; lni < 2; ++lni) st[smi][lni] = (f32x4){0.f, 0.f, 0.f, 0.f};
    for (int kk = 0; kk < HD; kk += 32) {
      bf16x8 a[2], bq[2];
      for (int smi = 0; smi < 2; ++smi) {
        const int r = sh + smi * 16 + l16;
        const int c = ((kk >> 3) + quad) ^ (r & 7);
        a[smi] = *(const bf16x8*)(sK + r * 64 + c * 8);
      }
      for (int lni = 0; lni < 2; ++lni) {
        const int r = lq + lni * 16 + l16;
        const int c = ((kk >> 3) + quad) ^ (r & 7);
        bq[lni] = *(const bf16x8*)(sQ + r * 64 + c * 8);
      }
      for (int smi = 0; smi < 2; ++smi)
        for (int lni = 0; lni < 2; ++lni)
          st[smi][lni] = mfma16(a[smi], bq[lni], st[smi][lni]);
    }

    for (int lni = 0; lni < 2; ++lni) {
      const int lrow = lq + lni * 16 + l16;
      for (int smi = 0; smi < 2; ++smi) {
        uint32_t u[4];
        for (int r = 0; r < 4; ++r) {
          union { float f; uint32_t i; } cv;
          cv.f = fast_sigmoid(st[smi][lni][r]);
          u[r] = cv.i + 0x8000u;  // round-half-up bf16
        }
        uint2 pk;
        pk.x = __builtin_amdgcn_perm(u[1], u[0], 0x07060302u);
        pk.y = __builtin_amdgcn_perm(u[3], u[2], 0x07060302u);
        *(uint2*)(sP + (size_t)lrow * 72 + sh + smi * 16 + quad * 4) = pk;
      }
    }
    __syncthreads();

    const int lr = wave * 16 + l16;
    for (int kk = 0; kk < 64; kk += 32) {
      bf16x8 ap = *(const bf16x8*)(sP + (size_t)lr * 72 + kk + quad * 8);
      for (int ni = 0; ni < 4; ++ni) {
        const int rd = ni * 16 + l16;
        const int c = ((kk >> 3) + quad) ^ (rd & 7);
        bf16x8 bv4 = *(const bf16x8*)(sV + rd * 64 + c * 8);
        oacc[ni] = mfma16(ap, bv4, oacc[ni]);
      }
      dacc = mfma16(ap, ones, dacc);
    }
  }

  for (int r = 0; r < 4; ++r) {
    const int lrow = l0 + wave * 16 + quad * 4 + r;
    const float rden = __builtin_amdgcn_rcpf(dacc[r] + 1e-4f);
    unsigned short* dst = oh + ((size_t)(b * L_SEQ + lrow)) * EMB + h * HD;
    for (int ni = 0; ni < 4; ++ni)
      dst[ni * 16 + l16] = f2bf_fast(oacc[ni][r] * rden);
  }
}

// ---------------------------------------------------------------- K3: avg
// 512 thr / 8 waves. Block = (s-tile 128, l-tile 128, b); grid 512 = 2/CU.
// Per head: 1 barrier, double-buffered Q/K staging, 32x32 MFMA, f32 accum.
__global__ __launch_bounds__(512) void k_avg(
    const unsigned short* __restrict__ qb, const unsigned short* __restrict__ kb,
    float* __restrict__ avg) {
  __shared__ __attribute__((aligned(16))) unsigned short sQ[2][128 * 64];
  __shared__ __attribute__((aligned(16))) unsigned short sK[2][128 * 64];
  const int ss0 = blockIdx.x * 128, l0 = blockIdx.y * 128, b = blockIdx.z;
  const int tid = threadIdx.x, wave = tid >> 6, lane = tid & 63;
  const int l32 = lane & 31, lh = lane >> 5;
  const int sr8 = lane >> 3, sc8 = lane & 7;
  const int mt = wave & 3;          // l-tile (32)
  const int ntg = (wave >> 2) * 2;  // first of 2 s-tiles (32 each)

  const unsigned short* qg0 = qb + ((size_t)(b * NHEAD) * L_SEQ + l0) * HD;
  const unsigned short* kg0 = kb + ((size_t)(b * NHEAD) * L_SEQ + ss0) * HD;
  const size_t hstride = (size_t)L_SEQ * HD;

  for (int i = 0; i < 2; ++i) {
    const int p = wave * 2 + i;
    const int r = p * 8 + sr8;
    const int c = sc8 ^ (r & 7);
    gl_lds16(qg0 + (size_t)r * HD + c * 8, sQ[0] + p * 512);
    gl_lds16(kg0 + (size_t)r * HD + c * 8, sK[0] + p * 512);
  }

  f32x16 av[2];
  for (int t = 0; t < 2; ++t)
    for (int i = 0; i < 16; ++i) av[t][i] = 0.f;

  for (int h = 0; h < NHEAD; ++h) {
    __syncthreads();  // buf(h) visible, prev reads done
    const int cur = h & 1;
    if (h < NHEAD - 1) {
      const int nxt = cur ^ 1;
      const unsigned short* qg = qg0 + (size_t)(h + 1) * hstride;
      const unsigned short* kg = kg0 + (size_t)(h + 1) * hstride;
      for (int i = 0; i < 2; ++i) {
        const int p = wave * 2 + i;
        const int r = p * 8 + sr8;
        const int c = sc8 ^ (r & 7);
        gl_lds16(qg + (size_t)r * HD + c * 8, sQ[nxt] + p * 512);
        gl_lds16(kg + (size_t)r * HD + c * 8, sK[nxt] + p * 512);
      }
    }

    f32x16 scr[2];
    for (int t = 0; t < 2; ++t)
      for (int i = 0; i < 16; ++i) scr[t][i] = 0.f;
    const int qrow = mt * 32 + l32;
    for (int kk = 0; kk < 4; ++kk) {
      const int cq = (kk * 2 + lh) ^ (qrow & 7);
      bf16x8 aq = *(const bf16x8*)(sQ[cur] + qrow * 64 + cq * 8);
      for (int t = 0; t < 2; ++t) {
        const int krow = (ntg + t) * 32 + l32;
        const int ck = (kk * 2 + lh) ^ (krow & 7);
        bf16x8 bk = *(const bf16x8*)(sK[cur] + krow * 64 + ck * 8);
        scr[t] = mfma32(aq, bk, scr[t]);
      }
    }
    for (int t = 0; t < 2; ++t)
      for (int r = 0; r < 16; ++r)
        av[t][r] += fast_sigmoid(scr[t][r]);
  }

  for (int t = 0; t < 2; ++t) {
    for (int r = 0; r < 16; ++r) {
      const int l = l0 + mt * 32 + (r & 3) + 8 * (r >> 2) + 4 * lh;
      const int s = ss0 + (ntg + t) * 32 + l32;
      avg[((size_t)b * L_SEQ + l) * L_SEQ + s] = av[t][r] * 0.0625f;
    }
  }
}

// ---------------------------------------------------------------- K4: outproj
__global__ __launch_bounds__(256) void k_outproj(
    const unsigned short* __restrict__ OH, const unsigned short* __restrict__ Wob,
    const float* __restrict__ ob, float* __restrict__ out) {
  __shared__ __attribute__((aligned(16))) unsigned short sA[128 * 32];
  __shared__ __attribute__((aligned(16))) unsigned short sB[128 * 32];
  const int n0 = blockIdx.x * 128, m0 = blockIdx.y * 128;
  f32x4 acc[4][4];
  gemm_core(OH, Wob, m0, n0, sA, sB, acc);

  const int tid = threadIdx.x, wave = tid >> 6, lane = tid & 63;
  const int quad = lane >> 4, l16 = lane & 15;
  const int wm = (wave >> 1) * 64, wn = (wave & 1) * 64;
  for (int ni = 0; ni < 4; ++ni) {
    const int n = n0 + wn + ni * 16 + l16;
    const float bv = ob[n];
    for (int mi = 0; mi < 4; ++mi) {
      for (int r = 0; r < 4; ++r) {
        const int m = m0 + wm + mi * 16 + quad * 4 + r;
        const int b = m >> 11, l = m & (L_SEQ - 1);
        out[((size_t)l * NBATCH + b) * EMB + n] = acc[mi][ni][r] + bv;
      }
    }
  }
}

extern "C" void kernel_launch(void* const* d_in, const int* in_sizes, int n_in,
                              void* d_out, int out_size, void* d_ws, size_t ws_size,
                              hipStream_t stream) {
  (void)in_sizes; (void)n_in; (void)out_size;
  const float* qin = (const float*)d_in[0];
  const float* kin = (const float*)d_in[1];
  const float* vin = (const float*)d_in[2];
  const float* w   = (const float*)d_in[3];
  const float* bias = (const float*)d_in[4];
  const float* wo  = (const float*)d_in[5];
  const float* ob  = (const float*)d_in[6];
  float* out = (float*)d_out;

  unsigned short* Xq  = (unsigned short*)d_ws;
  unsigned short* Xk  = Xq + (size_t)MROWS * EMB;
  unsigned short* Xv  = Xk + (size_t)MROWS * EMB;
  unsigned short* Wb  = Xv + (size_t)MROWS * EMB;
  unsigned short* Wob = Wb + (size_t)3 * EMB * EMB;
  unsigned short* qbuf = Wob + (size_t)EMB * EMB;
  unsigned short* kbuf = qbuf + (size_t)MROWS * EMB;
  unsigned short* vbuf = kbuf + (size_t)MROWS * EMB;
  unsigned short* ohb  = vbuf + (size_t)MROWS * EMB;
  const size_t need = ((size_t)MROWS * EMB * 7 + (size_t)4 * EMB * EMB) * 2;
  if (ws_size < need) return;

  k_convert<<<16384, 256, 0, stream>>>(qin, kin, vin, w, wo, Xq, Xk, Xv, Wb, Wob);
  k_inproj<<<dim3(8, 32, 3), 256, 0, stream>>>(Xq, Xk, Xv, Wb, bias, qbuf, kbuf, vbuf);
  k_attn<<<dim3(32, 16), 512, 0, stream>>>(qbuf, kbuf, vbuf, ohb);
  k_avg<<<dim3(16, 16, 2), 512, 0, stream>>>(qbuf, kbuf, out + (size_t)MROWS * EMB);
  k_outproj<<<dim3(8, 32), 256, 0, stream>>>(ohb, Wob, ob, out);
}

// Round 6
// 276.186 us; speedup vs baseline: 1.0504x; 1.0283x over previous
//
#include <hip/hip_runtime.h>
#include <stdint.h>

// SMHA: sigmoid multi-head attention, L=2048 B=2 E=1024 H=16 hd=64.
// convert(f32->bf16) -> inproj GEMM -> fused sigmoid attention
// -> avg_weights (head-summed sigmoid QK) -> outproj GEMM.

#define L_SEQ 2048
#define NBATCH 2
#define EMB 1024
#define NHEAD 16
#define HD 64
#define MROWS 4096  // B*L

typedef __bf16 bf16x8 __attribute__((ext_vector_type(8)));
typedef float f32x4 __attribute__((ext_vector_type(4)));
typedef float f32x16 __attribute__((ext_vector_type(16)));

__device__ __forceinline__ unsigned short f2bf(float f) {
  union { float f; uint32_t u; } v; v.f = f;
  uint32_t u = v.u;
  u += 0x7fffu + ((u >> 16) & 1u);  // RNE
  return (unsigned short)(u >> 16);
}

__device__ __forceinline__ unsigned short f2bf_fast(float f) {
  union { float f; uint32_t u; } v; v.f = f;
  return (unsigned short)((v.u + 0x8000u) >> 16);
}

__device__ __forceinline__ void gl_lds16(const void* gptr, void* ldsptr) {
  const uint32_t* g = reinterpret_cast<const uint32_t*>(gptr);
  auto* l = reinterpret_cast<__attribute__((address_space(3))) uint32_t*>(
      reinterpret_cast<uintptr_t>(ldsptr));
  __builtin_amdgcn_global_load_lds(g, l, 16, 0, 0);
}

__device__ __forceinline__ f32x4 mfma16(bf16x8 a, bf16x8 b, f32x4 c) {
  return __builtin_amdgcn_mfma_f32_16x16x32_bf16(a, b, c, 0, 0, 0);
}

__device__ __forceinline__ f32x16 mfma32(bf16x8 a, bf16x8 b, f32x16 c) {
  return __builtin_amdgcn_mfma_f32_32x32x16_bf16(a, b, c, 0, 0, 0);
}

__device__ __forceinline__ float fast_sigmoid(float x) {
  float e = __expf(-x);
  return __builtin_amdgcn_rcpf(1.0f + e);
}

// ---------------------------------------------------------------- K0: convert
__global__ __launch_bounds__(256) void k_convert(
    const float* __restrict__ qin, const float* __restrict__ kin,
    const float* __restrict__ vin, const float* __restrict__ win,
    const float* __restrict__ wo,
    unsigned short* __restrict__ Xq, unsigned short* __restrict__ Xk,
    unsigned short* __restrict__ Xv, unsigned short* __restrict__ Wb,
    unsigned short* __restrict__ Wob) {
  const int row = blockIdx.x;
  const int t = threadIdx.x;
  const float* src;
  unsigned short* dst;
  int srow;
  size_t drow;
  if (row < 3 * MROWS) {
    const int which = row >> 12;
    const int m = row & (MROWS - 1);
    const int b = m >> 11, l = m & (L_SEQ - 1);
    srow = l * NBATCH + b;  // input rows are (l, b)
    drow = (size_t)m;
    src = which == 0 ? qin : (which == 1 ? kin : vin);
    dst = which == 0 ? Xq : (which == 1 ? Xk : Xv);
  } else if (row < 3 * MROWS + 3072) {
    srow = row - 3 * MROWS; drow = (size_t)srow; src = win; dst = Wb;
  } else {
    srow = row - (3 * MROWS + 3072); drow = (size_t)srow; src = wo; dst = Wob;
  }
  const float4 vv = *(const float4*)(src + (size_t)srow * EMB + t * 4);
  ushort4 o;
  o.x = f2bf(vv.x); o.y = f2bf(vv.y); o.z = f2bf(vv.z); o.w = f2bf(vv.w);
  *(ushort4*)(dst + drow * EMB + t * 4) = o;
}

// ------------------------------------------ shared GEMM core (BT), dbuf, 1 barrier
// smem layout (shorts): sA0[0..4095] sA1[4096..] sB0[8192..] sB1[12288..]
__device__ __forceinline__ void gemm_core_db(
    const unsigned short* __restrict__ A, const unsigned short* __restrict__ Bm,
    int m0, int n0, unsigned short* smem, f32x4 acc[4][4]) {
  const int tid = threadIdx.x;
  const int wave = tid >> 6;
  const int lane = tid & 63;
  const int quad = lane >> 4;
  const int l16 = lane & 15;
  const int wm = (wave >> 1) * 64;
  const int wn = (wave & 1) * 64;
  const int srow = lane >> 2;
  const int scol = lane & 3;

  for (int mi = 0; mi < 4; ++mi)
    for (int ni = 0; ni < 4; ++ni)
      acc[mi][ni] = (f32x4){0.f, 0.f, 0.f, 0.f};

  // prologue: stage k0=0 into buf 0
  for (int i = 0; i < 2; ++i) {
    const int p = wave * 2 + i;
    const int r = p * 16 + srow;
    const int c = scol ^ ((r >> 1) & 3);
    gl_lds16(A + (size_t)(m0 + r) * EMB + c * 8, smem + p * 512);
    gl_lds16(Bm + (size_t)(n0 + r) * EMB + c * 8, smem + 8192 + p * 512);
  }

  int buf = 0;
  for (int k0 = 0; k0 < EMB; k0 += 32) {
    __syncthreads();  // buf(k0) DMA done; buf^1 readers (k0-32) done
    if (k0 + 32 < EMB) {
      const int nb = buf ^ 1;
      unsigned short* dA = smem + nb * 4096;
      unsigned short* dB = smem + 8192 + nb * 4096;
      for (int i = 0; i < 2; ++i) {
        const int p = wave * 2 + i;
        const int r = p * 16 + srow;
        const int c = scol ^ ((r >> 1) & 3);
        gl_lds16(A + (size_t)(m0 + r) * EMB + k0 + 32 + c * 8, dA + p * 512);
        gl_lds16(Bm + (size_t)(n0 + r) * EMB + k0 + 32 + c * 8, dB + p * 512);
      }
    }
    const unsigned short* rA = smem + buf * 4096;
    const unsigned short* rB = smem + 8192 + buf * 4096;
    bf16x8 af[4], bfr[4];
    for (int mi = 0; mi < 4; ++mi) {
      const int r = wm + mi * 16 + l16;
      const int cp = quad ^ ((r >> 1) & 3);
      af[mi] = *(const bf16x8*)(rA + r * 32 + cp * 8);
    }
    for (int ni = 0; ni < 4; ++ni) {
      const int r = wn + ni * 16 + l16;
      const int cp = quad ^ ((r >> 1) & 3);
      bfr[ni] = *(const bf16x8*)(rB + r * 32 + cp * 8);
    }
    for (int mi = 0; mi < 4; ++mi)
      for (int ni = 0; ni < 4; ++ni)
        acc[mi][ni] = mfma16(af[mi], bfr[ni], acc[mi][ni]);
    buf ^= 1;
  }
}

// ---------------------------------------------------------------- K1: inproj
// z=0: q (scaled 1/8) -> (b,h,l,d); z=1: k -> (b,h,l,d); z=2: v -> (b,h,d,l).
// Epilogues go through an LDS transpose tile (unioned with the dbuf buffers);
// stores use 8-lanes-per-128B-segment mapping (full cache lines per instr).
__global__ __launch_bounds__(256) void k_inproj(
    const unsigned short* __restrict__ Xq, const unsigned short* __restrict__ Xk,
    const unsigned short* __restrict__ Xv, const unsigned short* __restrict__ Wb,
    const float* __restrict__ bias,
    unsigned short* __restrict__ qb, unsigned short* __restrict__ kb,
    unsigned short* __restrict__ vb) {
  __shared__ __attribute__((aligned(16))) unsigned short smem[16384];  // 32 KB
  unsigned short* sT = smem;  // 128x128 transpose tile (epilogue reuse)
  const int z = blockIdx.z;
  const unsigned short* A = z == 0 ? Xq : (z == 1 ? Xk : Xv);
  const int n0 = blockIdx.x * 128, m0 = blockIdx.y * 128;
  f32x4 acc[4][4];
  gemm_core_db(A, Wb + (size_t)z * EMB * EMB, m0, n0, smem, acc);
  __syncthreads();  // loop reads done; smem reusable as sT

  const int tid = threadIdx.x, wave = tid >> 6, lane = tid & 63;
  const int quad = lane >> 4, l16 = lane & 15;
  const int wm = (wave >> 1) * 64, wn = (wave & 1) * 64;
  const int bb = m0 >> 11, lbase = m0 & (L_SEQ - 1);
  const int lane8 = tid & 7, rowid = tid >> 3;

  if (z == 2) {
    for (int ni = 0; ni < 4; ++ni) {
      const int n = wn + ni * 16 + l16;
      const float bv = bias[2 * EMB + n0 + n];
      const int x = (n & 15) << 1;
      for (int mi = 0; mi < 4; ++mi) {
        const int mchunk = ((wm + mi * 16) >> 2) + quad;
        const int slot = mchunk ^ x;
        ushort4 pk;
        pk.x = f2bf(acc[mi][ni][0] + bv);
        pk.y = f2bf(acc[mi][ni][1] + bv);
        pk.z = f2bf(acc[mi][ni][2] + bv);
        pk.w = f2bf(acc[mi][ni][3] + bv);
        *(ushort4*)(sT + (size_t)n * 128 + slot * 4) = pk;
      }
    }
    __syncthreads();
    for (int p = 0; p < 8; ++p) {
      const int row = rowid + p * 32;
      const int n = row >> 1, hf = row & 1;
      const int x = (n & 15) << 1;
      const int c2 = hf * 16 + lane8 * 2;
      const int slot = c2 ^ x;
      uint4 vd = *(const uint4*)(sT + (size_t)n * 128 + slot * 4);
      const int ng = n0 + n;
      const int h = ng >> 6, d = ng & 63;
      unsigned short* dst =
          vb + ((size_t)(bb * NHEAD + h) * HD + d) * L_SEQ + lbase + hf * 64;
      *(uint4*)(dst + lane8 * 8) = vd;
    }
  } else {
    const float scale = (z == 0) ? 0.125f : 1.0f;
    unsigned short* dstp = (z == 0) ? qb : kb;
    for (int ni = 0; ni < 4; ++ni) {
      const int n = wn + ni * 16 + l16;
      const float bv = bias[z * EMB + n0 + n];
      for (int mi = 0; mi < 4; ++mi) {
        for (int r = 0; r < 4; ++r) {
          const int m = wm + mi * 16 + quad * 4 + r;
          const int g = (m >> 2) & 7;
          sT[(size_t)m * 128 + (n ^ (g << 4))] =
              f2bf((acc[mi][ni][r] + bv) * scale);
        }
      }
    }
    __syncthreads();
    for (int p = 0; p < 8; ++p) {
      const int row = rowid + p * 32;
      const int l = row >> 1, hf = row & 1;
      const int g2 = ((l >> 2) & 7) << 1;
      const int c = hf * 8 + lane8;
      const int slot = c ^ g2;
      uint4 vd = *(const uint4*)(sT + (size_t)l * 128 + slot * 8);
      const int ng = n0 + c * 8;
      const int h = ng >> 6, d = ng & 63;
      unsigned short* dst =
          dstp + ((size_t)(bb * NHEAD + h) * L_SEQ + lbase + l) * HD + d;
      *(uint4*)dst = vd;
    }
  }
}

// --------------------------------------------------------------- K2: attention
// 512 thr / 8 waves; wave = (lq = wave&3 -> 32 l's, sh = wave>>2 -> 32 s's).
// QK: S^T 32x32 via mfma32. P converted C-layout -> PV A-frags IN REGISTERS
// (4 ds_bpermute/iter, lane^32 exchange). PV partial over wave's s-half;
// cross-(sh) oacc/den reconciliation once at epilogue via LDS. K/V double-
// buffered, ONE barrier per iter, DMA issued immediately after the barrier.
__global__ __launch_bounds__(512) void k_attn(
    const unsigned short* __restrict__ qb, const unsigned short* __restrict__ kb,
    const unsigned short* __restrict__ vb, unsigned short* __restrict__ oh) {
  __shared__ __attribute__((aligned(16))) unsigned short smem[25088];  // 49 KB
  unsigned short* sQ = smem;                 // 128x64
  float* sDen = (float*)(smem + 24576);      // 256 f32

  const int bh = blockIdx.x;
  const int b = bh >> 4, h = bh & 15;
  const int l0 = blockIdx.y * 128;
  const unsigned short* qg = qb + ((size_t)bh * L_SEQ + l0) * HD;
  const unsigned short* kg = kb + (size_t)bh * L_SEQ * HD;
  const unsigned short* vg = vb + (size_t)bh * HD * L_SEQ;

  const int tid = threadIdx.x, wave = tid >> 6, lane = tid & 63;
  const int l32 = lane & 31, lh = lane >> 5;
  const int sr8 = lane >> 3, sc8 = lane & 7;
  const int lq = wave & 3, sh = wave >> 2;
  const int pidx = (lane ^ 32) << 2;  // ds_bpermute byte index of partner lane

  // prologue: stage Q (16 chunks) + K/V iter0 (8+8 chunks) into buf 0
  for (int i = 0; i < 2; ++i) {
    const int p = wave * 2 + i;
    const int r = p * 8 + sr8;
    const int c = sc8 ^ (r & 7);
    gl_lds16(qg + (size_t)r * HD + c * 8, sQ + p * 512);
  }
  if (wave < 4) {
    for (int i = 0; i < 2; ++i) {
      const int p = wave * 2 + i;
      const int r = p * 8 + sr8;
      const int c = sc8 ^ (r & 7);
      gl_lds16(kg + (size_t)r * HD + c * 8, smem + 8192 + p * 512);
    }
  } else {
    for (int i = 0; i < 2; ++i) {
      const int p = (wave - 4) * 2 + i;
      const int r = p * 8 + sr8;
      const int c = sc8 ^ (r & 7);
      gl_lds16(vg + (size_t)r * L_SEQ + c * 8, smem + 16384 + p * 512);
    }
  }

  f32x16 oacc[2];
  for (int dh = 0; dh < 2; ++dh)
    for (int i = 0; i < 16; ++i) oacc[dh][i] = 0.f;
  float dp = 0.f;

  int buf = 0;
  const int rs = sh * 32 + l32;  // S^T row (s within 64-tile)
  const int rl = lq * 32 + l32;  // Q row (l within 128-tile)
  for (int it = 0; it < 32; ++it) {
    __syncthreads();  // buf DMA arrived; buf^1 readers done
    if (it < 31) {
      const int nb = buf ^ 1;
      const int s1 = (it + 1) * 64;
      if (wave < 4) {
        unsigned short* dK = smem + 8192 + nb * 4096;
        for (int i = 0; i < 2; ++i) {
          const int p = wave * 2 + i;
          const int r = p * 8 + sr8;
          const int c = sc8 ^ (r & 7);
          gl_lds16(kg + (size_t)(s1 + r) * HD + c * 8, dK + p * 512);
        }
      } else {
        unsigned short* dV = smem + 16384 + nb * 4096;
        for (int i = 0; i < 2; ++i) {
          const int p = (wave - 4) * 2 + i;
          const int r = p * 8 + sr8;
          const int c = sc8 ^ (r & 7);
          gl_lds16(vg + (size_t)r * L_SEQ + s1 + c * 8, dV + p * 512);
        }
      }
    }

    // QK: S^T tile (32 s x 32 l), K=64 over 4 mfma32
    f32x16 st;
    for (int i = 0; i < 16; ++i) st[i] = 0.f;
    const unsigned short* sKb = smem + 8192 + buf * 4096;
    #pragma unroll
    for (int kk = 0; kk < 4; ++kk) {
      const int ca = (2 * kk + lh) ^ (rs & 7);
      const int cb = (2 * kk + lh) ^ (rl & 7);
      bf16x8 a = *(const bf16x8*)(sKb + rs * 64 + ca * 8);
      bf16x8 q = *(const bf16x8*)(sQ + rl * 64 + cb * 8);
      st = mfma32(a, q, st);
    }

    // sigmoid + den partial + pack into 8 dwords (pairs of consecutive s)
    uint32_t pd[8];
    #pragma unroll
    for (int g = 0; g < 8; ++g) {
      const int rg = 4 * (g >> 1) + 2 * (g & 1);
      const float pa = fast_sigmoid(st[rg]);
      const float pb = fast_sigmoid(st[rg + 1]);
      dp += pa + pb;
      union { float f; uint32_t u; } ca, cb;
      ca.f = pa; cb.f = pb;
      pd[g] = __builtin_amdgcn_perm(cb.u + 0x8000u, ca.u + 0x8000u, 0x07060302u);
    }

    // PV over this wave's s-half: A-frag assembly via lane^32 exchange
    const unsigned short* sVb = smem + 16384 + buf * 4096;
    #pragma unroll
    for (int j = 0; j < 2; ++j) {
      const uint32_t s0 = lh ? pd[4 * j + 0] : pd[4 * j + 2];
      const uint32_t s1 = lh ? pd[4 * j + 1] : pd[4 * j + 3];
      const uint32_t r0 = (uint32_t)__builtin_amdgcn_ds_bpermute(pidx, (int)s0);
      const uint32_t r1 = (uint32_t)__builtin_amdgcn_ds_bpermute(pidx, (int)s1);
      union { uint32_t w[4]; bf16x8 v; } af;
      af.w[0] = lh ? r0 : pd[4 * j + 0];
      af.w[1] = lh ? r1 : pd[4 * j + 1];
      af.w[2] = lh ? pd[4 * j + 2] : r0;
      af.w[3] = lh ? pd[4 * j + 3] : r1;
      const int c8 = 4 * sh + 2 * j + lh;  // V column chunk (s)
      #pragma unroll
      for (int dh = 0; dh < 2; ++dh) {
        const int rd = dh * 32 + l32;
        bf16x8 bv = *(const bf16x8*)(sVb + rd * 64 + ((c8 ^ (rd & 7)) * 8));
        oacc[dh] = mfma32(af.v, bv, oacc[dh]);
      }
    }
    buf ^= 1;
  }

  // epilogue: reconcile sh pairs (oacc + den), normalize, store
  __syncthreads();  // final reads done; smem reusable
  float dp2 = dp + __shfl_xor(dp, 32, 64);
  if (lh == 0) sDen[sh * 128 + lq * 32 + l32] = dp2;
  float* scr = (float*)smem;  // 4 waves x 64 lanes x 36 floats (stride-padded)
  if (sh == 1) {
    float* w = scr + lq * 2304 + lane * 36;
    #pragma unroll
    for (int dh = 0; dh < 2; ++dh)
      for (int r = 0; r < 16; ++r) w[dh * 16 + r] = oacc[dh][r];
  }
  __syncthreads();
  if (sh == 0) {
    const float* rs2 = scr + lq * 2304 + lane * 36;
    #pragma unroll
    for (int dh = 0; dh < 2; ++dh)
      for (int r = 0; r < 16; ++r) oacc[dh][r] += rs2[dh * 16 + r];
    #pragma unroll
    for (int r = 0; r < 16; ++r) {
      const int l = lq * 32 + (r & 3) + 8 * (r >> 2) + 4 * lh;
      const float rden =
          __builtin_amdgcn_rcpf(sDen[l] + sDen[128 + l] + 1e-4f);
      unsigned short* dst = oh + ((size_t)(b * L_SEQ + l0 + l)) * EMB + h * HD;
      dst[l32] = f2bf_fast(oacc[0][r] * rden);
      dst[32 + l32] = f2bf_fast(oacc[1][r] * rden);
    }
  }
}

// ---------------------------------------------------------------- K3: avg
// 512 thr / 8 waves. Block = (s-tile 128, l-tile 128, b); grid 512 = 2/CU.
// Per head: 1 barrier, double-buffered Q/K staging, 32x32 MFMA, f32 accum.
__global__ __launch_bounds__(512) void k_avg(
    const unsigned short* __restrict__ qb, const unsigned short* __restrict__ kb,
    float* __restrict__ avg) {
  __shared__ __attribute__((aligned(16))) unsigned short smem[32768];  // 64 KB
  const int ss0 = blockIdx.x * 128, l0 = blockIdx.y * 128, b = blockIdx.z;
  const int tid = threadIdx.x, wave = tid >> 6, lane = tid & 63;
  const int l32 = lane & 31, lh = lane >> 5;
  const int sr8 = lane >> 3, sc8 = lane & 7;
  const int mt = wave & 3;          // l-tile (32)
  const int ntg = (wave >> 2) * 2;  // first of 2 s-tiles (32 each)

  const unsigned short* qg0 = qb + ((size_t)(b * NHEAD) * L_SEQ + l0) * HD;
  const unsigned short* kg0 = kb + ((size_t)(b * NHEAD) * L_SEQ + ss0) * HD;
  const size_t hstride = (size_t)L_SEQ * HD;

  // layout: sQ0[0] sQ1[8192] sK0[16384] sK1[24576]
  for (int i = 0; i < 2; ++i) {
    const int p = wave * 2 + i;
    const int r = p * 8 + sr8;
    const int c = sc8 ^ (r & 7);
    gl_lds16(qg0 + (size_t)r * HD + c * 8, smem + p * 512);
    gl_lds16(kg0 + (size_t)r * HD + c * 8, smem + 16384 + p * 512);
  }

  f32x16 av[2];
  for (int t = 0; t < 2; ++t)
    for (int i = 0; i < 16; ++i) av[t][i] = 0.f;

  for (int h = 0; h < NHEAD; ++h) {
    __syncthreads();  // buf(h) visible, prev reads done
    const int cur = h & 1;
    if (h < NHEAD - 1) {
      const int nxt = cur ^ 1;
      const unsigned short* qg = qg0 + (size_t)(h + 1) * hstride;
      const unsigned short* kg = kg0 + (size_t)(h + 1) * hstride;
      unsigned short* dQ = smem + nxt * 8192;
      unsigned short* dK = smem + 16384 + nxt * 8192;
      for (int i = 0; i < 2; ++i) {
        const int p = wave * 2 + i;
        const int r = p * 8 + sr8;
        const int c = sc8 ^ (r & 7);
        gl_lds16(qg + (size_t)r * HD + c * 8, dQ + p * 512);
        gl_lds16(kg + (size_t)r * HD + c * 8, dK + p * 512);
      }
    }

    const unsigned short* sQb = smem + cur * 8192;
    const unsigned short* sKb = smem + 16384 + cur * 8192;
    f32x16 scr[2];
    for (int t = 0; t < 2; ++t)
      for (int i = 0; i < 16; ++i) scr[t][i] = 0.f;
    const int qrow = mt * 32 + l32;
    for (int kk = 0; kk < 4; ++kk) {
      const int cq = (kk * 2 + lh) ^ (qrow & 7);
      bf16x8 aq = *(const bf16x8*)(sQb + qrow * 64 + cq * 8);
      for (int t = 0; t < 2; ++t) {
        const int krow = (ntg + t) * 32 + l32;
        const int ck = (kk * 2 + lh) ^ (krow & 7);
        bf16x8 bk = *(const bf16x8*)(sKb + krow * 64 + ck * 8);
        scr[t] = mfma32(aq, bk, scr[t]);
      }
    }
    for (int t = 0; t < 2; ++t)
      for (int r = 0; r < 16; ++r)
        av[t][r] += fast_sigmoid(scr[t][r]);
  }

  for (int t = 0; t < 2; ++t) {
    for (int r = 0; r < 16; ++r) {
      const int l = l0 + mt * 32 + (r & 3) + 8 * (r >> 2) + 4 * lh;
      const int s = ss0 + (ntg + t) * 32 + l32;
      avg[((size_t)b * L_SEQ + l) * L_SEQ + s] = av[t][r] * 0.0625f;
    }
  }
}

// ---------------------------------------------------------------- K4: outproj
__global__ __launch_bounds__(256) void k_outproj(
    const unsigned short* __restrict__ OH, const unsigned short* __restrict__ Wob,
    const float* __restrict__ ob, float* __restrict__ out) {
  __shared__ __attribute__((aligned(16))) unsigned short smem[16384];
  const int n0 = blockIdx.x * 128, m0 = blockIdx.y * 128;
  f32x4 acc[4][4];
  gemm_core_db(OH, Wob, m0, n0, smem, acc);

  const int tid = threadIdx.x, wave = tid >> 6, lane = tid & 63;
  const int quad = lane >> 4, l16 = lane & 15;
  const int wm = (wave >> 1) * 64, wn = (wave & 1) * 64;
  for (int ni = 0; ni < 4; ++ni) {
    const int n = n0 + wn + ni * 16 + l16;
    const float bv = ob[n];
    for (int mi = 0; mi < 4; ++mi) {
      for (int r = 0; r < 4; ++r) {
        const int m = m0 + wm + mi * 16 + quad * 4 + r;
        const int b = m >> 11, l = m & (L_SEQ - 1);
        out[((size_t)l * NBATCH + b) * EMB + n] = acc[mi][ni][r] + bv;
      }
    }
  }
}

extern "C" void kernel_launch(void* const* d_in, const int* in_sizes, int n_in,
                              void* d_out, int out_size, void* d_ws, size_t ws_size,
                              hipStream_t stream) {
  (void)in_sizes; (void)n_in; (void)out_size;
  const float* qin = (const float*)d_in[0];
  const float* kin = (const float*)d_in[1];
  const float* vin = (const float*)d_in[2];
  const float* w   = (const float*)d_in[3];
  const float* bias = (const float*)d_in[4];
  const float* wo  = (const float*)d_in[5];
  const float* ob  = (const float*)d_in[6];
  float* out = (float*)d_out;

  unsigned short* Xq  = (unsigned short*)d_ws;
  unsigned short* Xk  = Xq + (size_t)MROWS * EMB;
  unsigned short* Xv  = Xk + (size_t)MROWS * EMB;
  unsigned short* Wb  = Xv + (size_t)MROWS * EMB;
  unsigned short* Wob = Wb + (size_t)3 * EMB * EMB;
  unsigned short* qbuf = Wob + (size_t)EMB * EMB;
  unsigned short* kbuf = qbuf + (size_t)MROWS * EMB;
  unsigned short* vbuf = kbuf + (size_t)MROWS * EMB;
  unsigned short* ohb  = vbuf + (size_t)MROWS * EMB;
  const size_t need = ((size_t)MROWS * EMB * 7 + (size_t)4 * EMB * EMB) * 2;
  if (ws_size < need) return;

  k_convert<<<16384, 256, 0, stream>>>(qin, kin, vin, w, wo, Xq, Xk, Xv, Wb, Wob);
  k_inproj<<<dim3(8, 32, 3), 256, 0, stream>>>(Xq, Xk, Xv, Wb, bias, qbuf, kbuf, vbuf);
  k_attn<<<dim3(32, 16), 512, 0, stream>>>(qbuf, kbuf, vbuf, ohb);
  k_avg<<<dim3(16, 16, 2), 512, 0, stream>>>(qbuf, kbuf, out + (size_t)MROWS * EMB);
  k_outproj<<<dim3(8, 32), 256, 0, stream>>>(ohb, Wob, ob, out);
}